// Round 1
// baseline (110.309 us; speedup 1.0000x reference)
//
#include <hip/hip_runtime.h>

// YOLOv2 post-process: scores = sigmoid(obj)*sigmoid(cls) over 20,070,400 elems,
// exact top-100 (score desc, idx asc), box decode, class-offset NMS.
// Outputs (float32 flat, 700): bboxes[100*4] | scores[100] | labels[100] | keep[100]

#define NCLS      20
#define M_ANCH    (448*448*5)        // 1,003,520 anchors
#define NGROUPS   (M_ANCH*5)         // float4 groups over cls: 5,017,600
#define NBIN_LO   8000u              // histogram floor: score >= 0.25
#define NBINS     192
#define PASS1_BIN 8111u              // collect in pass1 if score >= 0.8671875
#define CAP       8192               // global candidate buffer entries
#define SELCAP    2048               // LDS selection buffer entries
#define KTOP      100
#define CONF      0.01f
#define NMS_T     0.5f
#define STRIDEF   32.0f
#define COFF      1000000.0f

__device__ __forceinline__ float sigm(float x) {
  return __builtin_amdgcn_rcpf(1.0f + __builtin_amdgcn_exp2f(-1.442695040888963f * x));
}
__device__ __forceinline__ float fexp(float x) {
  return __builtin_amdgcn_exp2f(1.442695040888963f * x);
}

// ws layout (bytes):
//   [0..16)        meta: {0:counter, 1:bstar, 2:need_pass2, 3:pad}
//   [16..16+768)   hist[192]
//   [1024..)       cscore[CAP] floats
//   [1024+CAP*4..) cidx[CAP] uints

__global__ void __launch_bounds__(256) k_zero(unsigned* meta, unsigned* hist) {
  int t = threadIdx.x;
  if (t < 4) meta[t] = 0u;
  for (int i = t; i < NBINS; i += 256) hist[i] = 0u;
}

__global__ void __launch_bounds__(256) k_pass1(const float* __restrict__ obj,
    const float* __restrict__ cls, unsigned* __restrict__ meta,
    unsigned* __restrict__ hist, float* __restrict__ cscore,
    unsigned* __restrict__ cidx) {
  __shared__ unsigned lh[NBINS];
  for (int i = threadIdx.x; i < NBINS; i += 256) lh[i] = 0u;
  __syncthreads();
  const int stride = gridDim.x * blockDim.x;
  for (int g = blockIdx.x * blockDim.x + threadIdx.x; g < NGROUPS; g += stride) {
    unsigned a = (unsigned)g / 5u;                 // anchor index
    float so = sigm(obj[a]);
    float4 c = ((const float4*)cls)[g];
    float ss[4];
    ss[0] = so * sigm(c.x); ss[1] = so * sigm(c.y);
    ss[2] = so * sigm(c.z); ss[3] = so * sigm(c.w);
    unsigned base = (unsigned)g * 4u;              // flat score index of ss[0]
#pragma unroll
    for (int j = 0; j < 4; ++j) {
      unsigned bin = __float_as_uint(ss[j]) >> 17; // monotone for positive floats
      if (bin >= NBIN_LO) {
        atomicAdd(&lh[bin - NBIN_LO], 1u);
        if (bin >= PASS1_BIN) {
          unsigned pos = atomicAdd(&meta[0], 1u);
          if (pos < CAP) { cscore[pos] = ss[j]; cidx[pos] = base + (unsigned)j; }
        }
      }
    }
  }
  __syncthreads();
  for (int i = threadIdx.x; i < NBINS; i += 256) {
    unsigned v = lh[i];
    if (v) atomicAdd(&hist[i], v);
  }
}

__global__ void k_thresh(unsigned* meta, const unsigned* hist) {
  if (threadIdx.x != 0) return;
  unsigned cum = 0, cumP1 = 0, bstar = NBIN_LO;
  bool found = false;
  for (int b = NBINS - 1; b >= 0; --b) {
    cum += hist[b];
    if (!found && cum >= (unsigned)KTOP) { bstar = NBIN_LO + (unsigned)b; found = true; }
    if (NBIN_LO + (unsigned)b == PASS1_BIN) cumP1 = cum;
  }
  meta[1] = bstar;
  // pass1 buffer is valid iff it covers bstar AND did not overflow
  unsigned need2 = (bstar < PASS1_BIN || cumP1 > CAP) ? 1u : 0u;
  meta[2] = need2;
  if (need2) meta[0] = 0u;   // reset counter for pass2 recollection
}

__global__ void __launch_bounds__(256) k_pass2(const float* __restrict__ obj,
    const float* __restrict__ cls, unsigned* __restrict__ meta,
    float* __restrict__ cscore, unsigned* __restrict__ cidx) {
  if (meta[2] == 0u) return;                       // expected fast path: exit
  const unsigned bstar = meta[1];
  const int stride = gridDim.x * blockDim.x;
  for (int g = blockIdx.x * blockDim.x + threadIdx.x; g < NGROUPS; g += stride) {
    unsigned a = (unsigned)g / 5u;
    float so = sigm(obj[a]);
    float4 c = ((const float4*)cls)[g];
    float ss[4];
    ss[0] = so * sigm(c.x); ss[1] = so * sigm(c.y);
    ss[2] = so * sigm(c.z); ss[3] = so * sigm(c.w);
    unsigned base = (unsigned)g * 4u;
#pragma unroll
    for (int j = 0; j < 4; ++j) {
      unsigned bin = __float_as_uint(ss[j]) >> 17;
      if (bin >= bstar) {
        unsigned pos = atomicAdd(&meta[0], 1u);
        if (pos < CAP) { cscore[pos] = ss[j]; cidx[pos] = base + (unsigned)j; }
      }
    }
  }
}

__global__ void __launch_bounds__(256) k_final(const float* __restrict__ reg,
    const float* __restrict__ anch, const unsigned* __restrict__ meta,
    const float* __restrict__ cscore, const unsigned* __restrict__ cidx,
    float* __restrict__ out) {
  __shared__ unsigned long long keys[SELCAP];
  __shared__ unsigned lcnt_s;
  __shared__ float sc[KTOP];
  __shared__ unsigned sid[KTOP];
  __shared__ float bx[KTOP][4];
  __shared__ float ob[KTOP][4];
  __shared__ float area[KTOP];
  __shared__ unsigned long long sup[KTOP][2];
  __shared__ unsigned long long keepm[2];
  const int tid = threadIdx.x;

  if (tid == 0) lcnt_s = 0u;
  if (tid < KTOP) { sc[tid] = 0.0f; sid[tid] = 0u; sup[tid][0] = 0ull; sup[tid][1] = 0ull; }
  __syncthreads();

  unsigned count = meta[0]; if (count > CAP) count = CAP;
  const unsigned bstar = meta[1];

  // compact: keep only candidates at/above the exact threshold bin
  for (unsigned t = (unsigned)tid; t < count; t += 256u) {
    float s = cscore[t];
    if ((__float_as_uint(s) >> 17) >= bstar) {
      unsigned p = atomicAdd(&lcnt_s, 1u);
      if (p < SELCAP)
        keys[p] = ((unsigned long long)__float_as_uint(s) << 32) |
                  (unsigned long long)(0xFFFFFFFFu - cidx[t]);   // idx asc on ties
    }
  }
  __syncthreads();
  unsigned lcnt = lcnt_s; if (lcnt > SELCAP) lcnt = SELCAP;

  // exact selection by rank counting (keys unique since idx unique)
  for (unsigned t = (unsigned)tid; t < lcnt; t += 256u) {
    unsigned long long k = keys[t];
    unsigned rank = 0;
    for (unsigned j = 0; j < lcnt; ++j) rank += (keys[j] > k) ? 1u : 0u;
    if (rank < (unsigned)KTOP) {
      sc[rank]  = __uint_as_float((unsigned)(k >> 32));
      sid[rank] = 0xFFFFFFFFu - (unsigned)(k & 0xFFFFFFFFull);
    }
  }
  __syncthreads();

  // decode boxes for top-100
  if (tid < KTOP) {
    unsigned idx = sid[tid];
    unsigned a = idx / 20u, lab = idx % 20u;
    float4 r  = ((const float4*)reg)[a];
    float4 an = ((const float4*)anch)[a];
    float cx = (sigm(r.x) + an.x) * STRIDEF;
    float cy = (sigm(r.y) + an.y) * STRIDEF;
    float w  = fexp(r.z) * an.z;
    float h  = fexp(r.w) * an.w;
    float x1 = cx - 0.5f * w, y1 = cy - 0.5f * h;
    float x2 = cx + 0.5f * w, y2 = cy + 0.5f * h;
    bx[tid][0] = x1; bx[tid][1] = y1; bx[tid][2] = x2; bx[tid][3] = y2;
    float off = (float)lab * COFF;
    float o0 = x1 + off, o1 = y1 + off, o2 = x2 + off, o3 = y2 + off;
    ob[tid][0] = o0; ob[tid][1] = o1; ob[tid][2] = o2; ob[tid][3] = o3;
    area[tid] = (o2 - o0) * (o3 - o1);
  }
  __syncthreads();

  // pairwise suppression mask (j > i only, per reference)
  for (int p = tid; p < KTOP * KTOP; p += 256) {
    int i = p / KTOP, j = p % KTOP;
    if (j > i) {
      float xx1 = fmaxf(ob[i][0], ob[j][0]);
      float yy1 = fmaxf(ob[i][1], ob[j][1]);
      float xx2 = fminf(ob[i][2], ob[j][2]);
      float yy2 = fminf(ob[i][3], ob[j][3]);
      float w = fmaxf(1e-10f, xx2 - xx1);
      float h = fmaxf(1e-10f, yy2 - yy1);
      float inter = w * h;
      float iou = inter / (area[i] + area[j] - inter);
      if (iou > NMS_T) atomicOr(&sup[i][j >> 6], 1ull << (j & 63));
    }
  }
  __syncthreads();

  // serial greedy NMS over bitmasks (exactly the reference fori_loop)
  if (tid == 0) {
    unsigned long long k0 = 0ull, k1 = 0ull;
    for (int t = 0; t < 64; ++t)    if (sc[t] > CONF) k0 |= (1ull << t);
    for (int t = 64; t < KTOP; ++t) if (sc[t] > CONF) k1 |= (1ull << (t - 64));
    for (int i = 0; i < KTOP; ++i) {
      bool ki = (i < 64) ? ((k0 >> i) & 1ull) : ((k1 >> (i - 64)) & 1ull);
      if (ki) { k0 &= ~sup[i][0]; k1 &= ~sup[i][1]; }
    }
    keepm[0] = k0; keepm[1] = k1;
  }
  __syncthreads();

  if (tid < KTOP) {
    out[tid * 4 + 0] = bx[tid][0];
    out[tid * 4 + 1] = bx[tid][1];
    out[tid * 4 + 2] = bx[tid][2];
    out[tid * 4 + 3] = bx[tid][3];
    out[400 + tid] = sc[tid];
    out[500 + tid] = (float)(sid[tid] % 20u);
    bool kp = (tid < 64) ? ((keepm[0] >> tid) & 1ull)
                         : ((keepm[1] >> (tid - 64)) & 1ull);
    out[600 + tid] = kp ? 1.0f : 0.0f;
  }
}

extern "C" void kernel_launch(void* const* d_in, const int* in_sizes, int n_in,
                              void* d_out, int out_size, void* d_ws, size_t ws_size,
                              hipStream_t stream) {
  (void)in_sizes; (void)n_in; (void)out_size; (void)ws_size;
  const float* obj  = (const float*)d_in[0];
  const float* cls  = (const float*)d_in[1];
  const float* reg  = (const float*)d_in[2];
  const float* anch = (const float*)d_in[3];
  float* out = (float*)d_out;

  unsigned* meta = (unsigned*)d_ws;
  unsigned* hist = meta + 4;
  float*    cscore = (float*)((char*)d_ws + 1024);
  unsigned* cidx   = (unsigned*)((char*)d_ws + 1024 + CAP * 4);

  hipLaunchKernelGGL(k_zero,   dim3(1),    dim3(256), 0, stream, meta, hist);
  hipLaunchKernelGGL(k_pass1,  dim3(2048), dim3(256), 0, stream, obj, cls, meta, hist, cscore, cidx);
  hipLaunchKernelGGL(k_thresh, dim3(1),    dim3(64),  0, stream, meta, hist);
  hipLaunchKernelGGL(k_pass2,  dim3(2048), dim3(256), 0, stream, obj, cls, meta, cscore, cidx);
  hipLaunchKernelGGL(k_final,  dim3(1),    dim3(256), 0, stream, reg, anch, meta, cscore, cidx, out);
}

// Round 2
// 107.220 us; speedup vs baseline: 1.0288x; 1.0288x over previous
//
#include <hip/hip_runtime.h>

// YOLOv2 post-process. Key insight: score = sigm(obj)*sigm(cls), both factors < 1,
// so score >= T requires obj >= logit(T) AND cls >= logit(T). Prefilter on obj
// skips 97.4% of the 80MB cls read at T=0.86. Exact top-100 among all elements
// >= T (valid whenever count >= 100); histogram rescue path for generality.
// Outputs (float32 flat, 700): bboxes[100*4] | scores[100] | labels[100] | keep[100]

#define KTOP    100
#define CAP     4096u
#define LBUF    128
#define NANCH   1003520u       // 448*448*5
#define NQ      250880u        // NANCH/4 (exact)
#define THRF    0.86f          // collect threshold on score
#define PRE_T   1.80f          // conservative logit prefilter: sigm(1.80)=0.8581 < 0.86
#define CONF    0.01f
#define NMS_T   0.5f
#define STRIDEF 32.0f
#define COFF    1000000.0f

// ws layout (bytes):
//   [0..16)      meta: {0:count, 1:bstar, 2:need_rescue, 3:overflow}
//   [64..16448)  hist[4096] (rescue only)
//   [16448..)    cscore[CAP] floats
//   [32832..)    cidx[CAP] uints            (total 49216 <= 66560 proven available)

__device__ __forceinline__ float sigm(float x) {
  return __builtin_amdgcn_rcpf(1.0f + __builtin_amdgcn_exp2f(-1.442695040888963f * x));
}
__device__ __forceinline__ float fexp(float x) {
  return __builtin_amdgcn_exp2f(1.442695040888963f * x);
}

// ---- hot path: obj-prefiltered threshold collect, no histogram ----
__global__ void __launch_bounds__(256) k_scan(const float* __restrict__ obj,
    const float* __restrict__ cls, unsigned* __restrict__ meta,
    float* __restrict__ cscore, unsigned* __restrict__ cidx) {
  __shared__ float lsc[LBUF];
  __shared__ unsigned lid[LBUF];
  __shared__ unsigned lcnt;
  __shared__ unsigned gbase;
  const int tid = threadIdx.x;
  if (tid == 0) lcnt = 0u;
  __syncthreads();

  unsigned q = blockIdx.x * 256u + (unsigned)tid;   // q < NQ, grid sized exactly
  float4 o4 = ((const float4*)obj)[q];
  float ov[4] = {o4.x, o4.y, o4.z, o4.w};
#pragma unroll
  for (int k = 0; k < 4; ++k) {
    if (ov[k] < PRE_T) continue;                    // sigm(obj) < 0.8581 -> score < 0.86
    unsigned a = q * 4u + (unsigned)k;
    float so = sigm(ov[k]);
    const float4* cp = (const float4*)(cls + (size_t)a * 20u);
#pragma unroll
    for (int v = 0; v < 5; ++v) {
      float4 c = cp[v];
      float cc[4] = {c.x, c.y, c.z, c.w};
#pragma unroll
      for (int j = 0; j < 4; ++j) {
        if (cc[j] < PRE_T) continue;                // sigm(cls) < 0.8581 -> score < 0.86
        float s = so * sigm(cc[j]);
        if (s >= THRF) {
          unsigned p = atomicAdd(&lcnt, 1u);
          if (p < LBUF) { lsc[p] = s; lid[p] = a * 20u + (unsigned)(v * 4 + j); }
        }
      }
    }
  }
  __syncthreads();
  unsigned n = lcnt > LBUF ? LBUF : lcnt;
  if (tid == 0) {
    if (lcnt > LBUF) atomicOr(&meta[3], 1u);
    gbase = n ? atomicAdd(&meta[0], n) : 0u;
  }
  __syncthreads();
  for (unsigned t = (unsigned)tid; t < n; t += 256u) {
    unsigned p = gbase + t;
    if (p < CAP) { cscore[p] = lsc[t]; cidx[p] = lid[t]; }
    else atomicOr(&meta[3], 1u);
  }
}

// ---- decide whether rescue is needed; prep rescue state ----
__global__ void __launch_bounds__(256) k_check(unsigned* __restrict__ meta,
                                               unsigned* __restrict__ hist) {
  unsigned cnt = meta[0], ovf = meta[3];
  unsigned need = (cnt < (unsigned)KTOP || cnt > CAP || ovf) ? 1u : 0u;
  __syncthreads();
  if (threadIdx.x == 0) meta[2] = need;
  if (need) {
    for (unsigned i = threadIdx.x; i < 4096u; i += 256u) hist[i] = 0u;
    if (threadIdx.x == 0) meta[0] = 0u;
  }
}

// ---- rescue path (early-exits when not needed) ----
__global__ void __launch_bounds__(256) k_rhist(const float* __restrict__ obj,
    const float* __restrict__ cls, const unsigned* __restrict__ meta,
    unsigned* __restrict__ hist) {
  if (meta[2] == 0u) return;
  __shared__ unsigned lh[4096];
  for (int i = threadIdx.x; i < 4096; i += 256) lh[i] = 0u;
  __syncthreads();
  unsigned q = blockIdx.x * 256u + (unsigned)threadIdx.x;
  float4 o4 = ((const float4*)obj)[q];
  float ov[4] = {o4.x, o4.y, o4.z, o4.w};
  for (int k = 0; k < 4; ++k) {
    float so = sigm(ov[k]);
    unsigned a = q * 4u + (unsigned)k;
    const float4* cp = (const float4*)(cls + (size_t)a * 20u);
    for (int v = 0; v < 5; ++v) {
      float4 c = cp[v];
      float cc[4] = {c.x, c.y, c.z, c.w};
      for (int j = 0; j < 4; ++j) {
        float s = so * sigm(cc[j]);
        atomicAdd(&lh[__float_as_uint(s) >> 19], 1u);  // monotone bin, <4096 for s<2^64
      }
    }
  }
  __syncthreads();
  for (int i = threadIdx.x; i < 4096; i += 256) {
    unsigned v = lh[i];
    if (v) atomicAdd(&hist[i], v);
  }
}

__global__ void __launch_bounds__(256) k_rbstar(unsigned* __restrict__ meta,
                                                const unsigned* __restrict__ hist) {
  if (meta[2] == 0u) return;
  __shared__ unsigned part[256];
  const int tid = threadIdx.x;
  unsigned s = 0;
  for (int i = 0; i < 16; ++i) s += hist[tid * 16 + i];
  part[tid] = s;
  __syncthreads();
  if (tid == 0) {
    unsigned cum = 0; int seg = 0; bool found = false;
    for (int i = 255; i >= 0; --i) {
      cum += part[i];
      if (cum >= (unsigned)KTOP) { seg = i; found = true; break; }
    }
    unsigned bs = 0u;
    if (found) {
      unsigned cumAbove = 0;
      for (int i = seg + 1; i < 256; ++i) cumAbove += part[i];
      unsigned c = cumAbove;
      for (int b = seg * 16 + 15; b >= seg * 16; --b) {
        c += hist[b];
        if (c >= (unsigned)KTOP) { bs = (unsigned)b; break; }
      }
    }
    meta[1] = bs;
  }
}

__global__ void __launch_bounds__(256) k_rcollect(const float* __restrict__ obj,
    const float* __restrict__ cls, unsigned* __restrict__ meta,
    float* __restrict__ cscore, unsigned* __restrict__ cidx) {
  if (meta[2] == 0u) return;
  const unsigned bstar = meta[1];
  unsigned q = blockIdx.x * 256u + (unsigned)threadIdx.x;
  float4 o4 = ((const float4*)obj)[q];
  float ov[4] = {o4.x, o4.y, o4.z, o4.w};
  for (int k = 0; k < 4; ++k) {
    float so = sigm(ov[k]);
    unsigned a = q * 4u + (unsigned)k;
    const float4* cp = (const float4*)(cls + (size_t)a * 20u);
    for (int v = 0; v < 5; ++v) {
      float4 c = cp[v];
      float cc[4] = {c.x, c.y, c.z, c.w};
      for (int j = 0; j < 4; ++j) {
        float s = so * sigm(cc[j]);
        if ((__float_as_uint(s) >> 19) >= bstar) {
          unsigned p = atomicAdd(&meta[0], 1u);
          if (p < CAP) { cscore[p] = s; cidx[p] = a * 20u + (unsigned)(v * 4 + j); }
        }
      }
    }
  }
}

// ---- exact top-100 selection, decode, NMS, output ----
__global__ void __launch_bounds__(1024) k_final(const float* __restrict__ reg,
    const float* __restrict__ anch, const unsigned* __restrict__ meta,
    const float* __restrict__ cscore, const unsigned* __restrict__ cidx,
    float* __restrict__ out) {
  __shared__ unsigned long long keys[CAP];   // 32 KiB
  __shared__ float sc[KTOP];
  __shared__ unsigned sid[KTOP];
  __shared__ float bx[KTOP][4];
  __shared__ float ob[KTOP][4];
  __shared__ float area[KTOP];
  __shared__ unsigned long long sup[KTOP][2];
  __shared__ unsigned long long keepm[2];
  const int tid = threadIdx.x;

  if (tid < KTOP) { sc[tid] = 0.0f; sid[tid] = 0u; sup[tid][0] = 0ull; sup[tid][1] = 0ull; }

  unsigned count = meta[0]; if (count > CAP) count = CAP;
  for (unsigned t = (unsigned)tid; t < count; t += 1024u)
    keys[t] = ((unsigned long long)__float_as_uint(cscore[t]) << 32) |
              (unsigned long long)(0xFFFFFFFFu - cidx[t]);   // idx asc on score ties
  __syncthreads();

  // exact rank counting (keys unique since idx unique); inner reads broadcast from LDS
  for (unsigned t = (unsigned)tid; t < count; t += 1024u) {
    unsigned long long k = keys[t];
    unsigned rank = 0;
    for (unsigned j = 0; j < count; ++j) rank += (keys[j] > k) ? 1u : 0u;
    if (rank < (unsigned)KTOP) {
      sc[rank]  = __uint_as_float((unsigned)(k >> 32));
      sid[rank] = 0xFFFFFFFFu - (unsigned)(k & 0xFFFFFFFFull);
    }
  }
  __syncthreads();

  // decode boxes for top-100
  if (tid < KTOP) {
    unsigned idx = sid[tid];
    unsigned a = idx / 20u, lab = idx % 20u;
    float4 r  = ((const float4*)reg)[a];
    float4 an = ((const float4*)anch)[a];
    float cx = (sigm(r.x) + an.x) * STRIDEF;
    float cy = (sigm(r.y) + an.y) * STRIDEF;
    float w  = fexp(r.z) * an.z;
    float h  = fexp(r.w) * an.w;
    float x1 = cx - 0.5f * w, y1 = cy - 0.5f * h;
    float x2 = cx + 0.5f * w, y2 = cy + 0.5f * h;
    bx[tid][0] = x1; bx[tid][1] = y1; bx[tid][2] = x2; bx[tid][3] = y2;
    float off = (float)lab * COFF;
    float o0 = x1 + off, o1 = y1 + off, o2 = x2 + off, o3 = y2 + off;
    ob[tid][0] = o0; ob[tid][1] = o1; ob[tid][2] = o2; ob[tid][3] = o3;
    area[tid] = (o2 - o0) * (o3 - o1);
  }
  __syncthreads();

  // pairwise suppression mask (j > i only, per reference)
  for (int p = tid; p < KTOP * KTOP; p += 1024) {
    int i = p / KTOP, j = p % KTOP;
    if (j > i) {
      float xx1 = fmaxf(ob[i][0], ob[j][0]);
      float yy1 = fmaxf(ob[i][1], ob[j][1]);
      float xx2 = fminf(ob[i][2], ob[j][2]);
      float yy2 = fminf(ob[i][3], ob[j][3]);
      float w = fmaxf(1e-10f, xx2 - xx1);
      float h = fmaxf(1e-10f, yy2 - yy1);
      float inter = w * h;
      float iou = inter / (area[i] + area[j] - inter);
      if (iou > NMS_T) atomicOr(&sup[i][j >> 6], 1ull << (j & 63));
    }
  }
  __syncthreads();

  // serial greedy NMS over bitmasks (exactly the reference fori_loop)
  if (tid == 0) {
    unsigned long long k0 = 0ull, k1 = 0ull;
    for (int t = 0; t < 64; ++t)    if (sc[t] > CONF) k0 |= (1ull << t);
    for (int t = 64; t < KTOP; ++t) if (sc[t] > CONF) k1 |= (1ull << (t - 64));
    for (int i = 0; i < KTOP; ++i) {
      bool ki = (i < 64) ? ((k0 >> i) & 1ull) : ((k1 >> (i - 64)) & 1ull);
      if (ki) { k0 &= ~sup[i][0]; k1 &= ~sup[i][1]; }
    }
    keepm[0] = k0; keepm[1] = k1;
  }
  __syncthreads();

  if (tid < KTOP) {
    out[tid * 4 + 0] = bx[tid][0];
    out[tid * 4 + 1] = bx[tid][1];
    out[tid * 4 + 2] = bx[tid][2];
    out[tid * 4 + 3] = bx[tid][3];
    out[400 + tid] = sc[tid];
    out[500 + tid] = (float)(sid[tid] % 20u);
    bool kp = (tid < 64) ? ((keepm[0] >> tid) & 1ull)
                         : ((keepm[1] >> (tid - 64)) & 1ull);
    out[600 + tid] = kp ? 1.0f : 0.0f;
  }
}

extern "C" void kernel_launch(void* const* d_in, const int* in_sizes, int n_in,
                              void* d_out, int out_size, void* d_ws, size_t ws_size,
                              hipStream_t stream) {
  (void)in_sizes; (void)n_in; (void)out_size; (void)ws_size;
  const float* obj  = (const float*)d_in[0];
  const float* cls  = (const float*)d_in[1];
  const float* reg  = (const float*)d_in[2];
  const float* anch = (const float*)d_in[3];
  float* out = (float*)d_out;

  unsigned* meta   = (unsigned*)d_ws;
  unsigned* hist   = (unsigned*)((char*)d_ws + 64);
  float*    cscore = (float*)((char*)d_ws + 16448);
  unsigned* cidx   = (unsigned*)((char*)d_ws + 32832);

  hipMemsetAsync(meta, 0, 16, stream);
  hipLaunchKernelGGL(k_scan,     dim3(NQ / 256), dim3(256),  0, stream, obj, cls, meta, cscore, cidx);
  hipLaunchKernelGGL(k_check,    dim3(1),        dim3(256),  0, stream, meta, hist);
  hipLaunchKernelGGL(k_rhist,    dim3(NQ / 256), dim3(256),  0, stream, obj, cls, meta, hist);
  hipLaunchKernelGGL(k_rbstar,   dim3(1),        dim3(256),  0, stream, meta, hist);
  hipLaunchKernelGGL(k_rcollect, dim3(NQ / 256), dim3(256),  0, stream, obj, cls, meta, cscore, cidx);
  hipLaunchKernelGGL(k_final,    dim3(1),        dim3(1024), 0, stream, reg, anch, meta, cscore, cidx, out);
}

// Round 3
// 54.937 us; speedup vs baseline: 2.0079x; 1.9517x over previous
//
#include <hip/hip_runtime.h>

// YOLOv2 post-process. score = sigm(obj)*sigm(cls), both factors < 1, so
// score >= T requires obj >= logit(T) AND cls >= logit(T). Obj-prefilter skips
// 97.4% of the 80MB cls read at T=0.86. Exact top-100 among collected
// candidates via fine-histogram refine (n ~1100 -> ~110) + rank counting.
// Histogram rescue path preserves correctness if count < 100 or buffer overflow.
// Outputs (float32 flat, 700): bboxes[100*4] | scores[100] | labels[100] | keep[100]

#define KTOP    100
#define CAP     4096u
#define LBUF    128
#define SELN    512
#define NANCH   1003520u       // 448*448*5
#define NQ      250880u        // NANCH/4 (exact)
#define THRF    0.86f          // collect threshold on score
#define PRE_T   1.80f          // conservative logit prefilter: sigm(1.80)=0.8581 < 0.86
#define CONF    0.01f
#define NMS_T   0.5f
#define STRIDEF 32.0f
#define COFF    1000000.0f

// ws layout (bytes):
//   [0..16)      meta: {0:count, 1:bstar, 2:need_rescue, 3:overflow}
//   [64..16448)  hist[4096] (rescue only)
//   [16448..)    cscore[CAP] floats
//   [32832..)    cidx[CAP] uints

__device__ __forceinline__ float sigm(float x) {
  return __builtin_amdgcn_rcpf(1.0f + __builtin_amdgcn_exp2f(-1.442695040888963f * x));
}
__device__ __forceinline__ float fexp(float x) {
  return __builtin_amdgcn_exp2f(1.442695040888963f * x);
}

// ---- hot path: obj-prefiltered threshold collect ----
__global__ void __launch_bounds__(256) k_scan(const float* __restrict__ obj,
    const float* __restrict__ cls, unsigned* __restrict__ meta,
    float* __restrict__ cscore, unsigned* __restrict__ cidx) {
  __shared__ float lsc[LBUF];
  __shared__ unsigned lid[LBUF];
  __shared__ unsigned lcnt;
  __shared__ unsigned gbase;
  const int tid = threadIdx.x;
  if (tid == 0) lcnt = 0u;
  __syncthreads();

  unsigned q = blockIdx.x * 256u + (unsigned)tid;   // q < NQ, grid sized exactly
  float4 o4 = ((const float4*)obj)[q];
  float ov[4] = {o4.x, o4.y, o4.z, o4.w};
#pragma unroll
  for (int k = 0; k < 4; ++k) {
    if (ov[k] < PRE_T) continue;                    // sigm(obj) < 0.8581 -> score < 0.86
    unsigned a = q * 4u + (unsigned)k;
    float so = sigm(ov[k]);
    const float4* cp = (const float4*)(cls + (size_t)a * 20u);
#pragma unroll
    for (int v = 0; v < 5; ++v) {
      float4 c = cp[v];
      float cc[4] = {c.x, c.y, c.z, c.w};
#pragma unroll
      for (int j = 0; j < 4; ++j) {
        if (cc[j] < PRE_T) continue;
        float s = so * sigm(cc[j]);
        if (s >= THRF) {
          unsigned p = atomicAdd(&lcnt, 1u);
          if (p < LBUF) { lsc[p] = s; lid[p] = a * 20u + (unsigned)(v * 4 + j); }
        }
      }
    }
  }
  __syncthreads();
  unsigned n = lcnt > LBUF ? LBUF : lcnt;
  if (tid == 0) {
    if (lcnt > LBUF) atomicOr(&meta[3], 1u);
    gbase = n ? atomicAdd(&meta[0], n) : 0u;
  }
  __syncthreads();
  for (unsigned t = (unsigned)tid; t < n; t += 256u) {
    unsigned p = gbase + t;
    if (p < CAP) { cscore[p] = lsc[t]; cidx[p] = lid[t]; }
    else atomicOr(&meta[3], 1u);
  }
}

// ---- decide whether rescue is needed; prep rescue state ----
__global__ void __launch_bounds__(256) k_check(unsigned* __restrict__ meta,
                                               unsigned* __restrict__ hist) {
  unsigned cnt = meta[0], ovf = meta[3];
  unsigned need = (cnt < (unsigned)KTOP || cnt > CAP || ovf) ? 1u : 0u;
  __syncthreads();
  if (threadIdx.x == 0) meta[2] = need;
  if (need) {
    for (unsigned i = threadIdx.x; i < 4096u; i += 256u) hist[i] = 0u;
    if (threadIdx.x == 0) meta[0] = 0u;
  }
}

// ---- rescue path (dead in practice; grid-stride to keep dead-dispatch cheap) ----
__global__ void __launch_bounds__(256) k_rhist(const float* __restrict__ obj,
    const float* __restrict__ cls, const unsigned* __restrict__ meta,
    unsigned* __restrict__ hist) {
  if (meta[2] == 0u) return;
  __shared__ unsigned lh[4096];
  for (int i = threadIdx.x; i < 4096; i += 256) lh[i] = 0u;
  __syncthreads();
  for (unsigned q = blockIdx.x * 256u + (unsigned)threadIdx.x; q < NQ;
       q += gridDim.x * 256u) {
    float4 o4 = ((const float4*)obj)[q];
    float ov[4] = {o4.x, o4.y, o4.z, o4.w};
    for (int k = 0; k < 4; ++k) {
      float so = sigm(ov[k]);
      unsigned a = q * 4u + (unsigned)k;
      const float4* cp = (const float4*)(cls + (size_t)a * 20u);
      for (int v = 0; v < 5; ++v) {
        float4 c = cp[v];
        float cc[4] = {c.x, c.y, c.z, c.w};
        for (int j = 0; j < 4; ++j) {
          float s = so * sigm(cc[j]);
          atomicAdd(&lh[__float_as_uint(s) >> 19], 1u);
        }
      }
    }
  }
  __syncthreads();
  for (int i = threadIdx.x; i < 4096; i += 256) {
    unsigned v = lh[i];
    if (v) atomicAdd(&hist[i], v);
  }
}

__global__ void __launch_bounds__(256) k_rbstar(unsigned* __restrict__ meta,
                                                const unsigned* __restrict__ hist) {
  if (meta[2] == 0u) return;
  __shared__ unsigned part[256];
  const int tid = threadIdx.x;
  unsigned s = 0;
  for (int i = 0; i < 16; ++i) s += hist[tid * 16 + i];
  part[tid] = s;
  __syncthreads();
  if (tid == 0) {
    unsigned cum = 0; int seg = 0; bool found = false;
    for (int i = 255; i >= 0; --i) {
      cum += part[i];
      if (cum >= (unsigned)KTOP) { seg = i; found = true; break; }
    }
    unsigned bs = 0u;
    if (found) {
      unsigned cumAbove = 0;
      for (int i = seg + 1; i < 256; ++i) cumAbove += part[i];
      unsigned c = cumAbove;
      for (int b = seg * 16 + 15; b >= seg * 16; --b) {
        c += hist[b];
        if (c >= (unsigned)KTOP) { bs = (unsigned)b; break; }
      }
    }
    meta[1] = bs;
  }
}

__global__ void __launch_bounds__(256) k_rcollect(const float* __restrict__ obj,
    const float* __restrict__ cls, unsigned* __restrict__ meta,
    float* __restrict__ cscore, unsigned* __restrict__ cidx) {
  if (meta[2] == 0u) return;
  const unsigned bstar = meta[1];
  for (unsigned q = blockIdx.x * 256u + (unsigned)threadIdx.x; q < NQ;
       q += gridDim.x * 256u) {
    float4 o4 = ((const float4*)obj)[q];
    float ov[4] = {o4.x, o4.y, o4.z, o4.w};
    for (int k = 0; k < 4; ++k) {
      float so = sigm(ov[k]);
      unsigned a = q * 4u + (unsigned)k;
      const float4* cp = (const float4*)(cls + (size_t)a * 20u);
      for (int v = 0; v < 5; ++v) {
        float4 c = cp[v];
        float cc[4] = {c.x, c.y, c.z, c.w};
        for (int j = 0; j < 4; ++j) {
          float s = so * sigm(cc[j]);
          if ((__float_as_uint(s) >> 19) >= bstar) {
            unsigned p = atomicAdd(&meta[0], 1u);
            if (p < CAP) { cscore[p] = s; cidx[p] = a * 20u + (unsigned)(v * 4 + j); }
          }
        }
      }
    }
  }
}

// ---- exact top-100: histogram refine -> rank count -> decode -> NMS ----
__global__ void __launch_bounds__(1024) k_final(const float* __restrict__ reg,
    const float* __restrict__ anch, const unsigned* __restrict__ meta,
    const float* __restrict__ cscore, const unsigned* __restrict__ cidx,
    float* __restrict__ out) {
  __shared__ unsigned long long keys[CAP];     // 32 KiB
  __shared__ unsigned long long selk[SELN];    // 4 KiB
  __shared__ unsigned fhist[512];              // 2 KiB
  __shared__ unsigned scnt, bstar_s, nsel_s;
  __shared__ float sc[KTOP];
  __shared__ unsigned sid[KTOP];
  __shared__ float bx[KTOP][4];
  __shared__ float ob[KTOP][4];
  __shared__ float area[KTOP];
  __shared__ unsigned long long sup[KTOP][2];
  __shared__ unsigned long long keepm[2];
  const int tid = threadIdx.x;

  if (tid < KTOP) { sc[tid] = 0.0f; sid[tid] = 0u; sup[tid][0] = 0ull; sup[tid][1] = 0ull; }
  if (tid < 512) fhist[tid] = 0u;
  if (tid == 0) scnt = 0u;
  __syncthreads();

  unsigned count = meta[0]; if (count > CAP) count = CAP;
  // load keys + fine histogram. bin = (bits>>14)-64512 is exact+monotone on [0.5,1);
  // scores <0.5 (rescue only) clamp to bin 0 -> full-set fallback (correct, slow).
  for (unsigned t = (unsigned)tid; t < count; t += 1024u) {
    float s = cscore[t];
    keys[t] = ((unsigned long long)__float_as_uint(s) << 32) |
              (unsigned long long)(0xFFFFFFFFu - cidx[t]);   // idx asc on score ties
    int bin = (int)(__float_as_uint(s) >> 14) - 64512;
    bin = bin < 0 ? 0 : (bin > 511 ? 511 : bin);
    atomicAdd(&fhist[bin], 1u);
  }
  __syncthreads();

  if (tid == 0) {
    unsigned cum = 0; int b = 511;
    for (; b >= 0; --b) { cum += fhist[b]; if (cum >= (unsigned)KTOP) break; }
    bstar_s = (b < 0) ? 0u : (unsigned)b;
    nsel_s  = cum;                    // count in bins >= bstar (>=100 unless count<100)
  }
  __syncthreads();
  const unsigned bstar = bstar_s;
  const bool small = (nsel_s <= (unsigned)SELN);

  if (small) {  // compact survivors (typical ~110)
    for (unsigned t = (unsigned)tid; t < count; t += 1024u) {
      unsigned bits = (unsigned)(keys[t] >> 32);
      int bin = (int)(bits >> 14) - 64512;
      bin = bin < 0 ? 0 : (bin > 511 ? 511 : bin);
      if ((unsigned)bin >= bstar) {
        unsigned p = atomicAdd(&scnt, 1u);
        if (p < (unsigned)SELN) selk[p] = keys[t];
      }
    }
  }
  __syncthreads();
  const unsigned long long* sp = small ? selk : keys;
  unsigned n = small ? (scnt > (unsigned)SELN ? (unsigned)SELN : scnt) : count;

  // exact rank counting among survivors (global top-100 == survivor top-100)
  for (unsigned t = (unsigned)tid; t < n; t += 1024u) {
    unsigned long long k = sp[t];
    unsigned rank = 0;
    for (unsigned j = 0; j < n; ++j) rank += (sp[j] > k) ? 1u : 0u;
    if (rank < (unsigned)KTOP) {
      sc[rank]  = __uint_as_float((unsigned)(k >> 32));
      sid[rank] = 0xFFFFFFFFu - (unsigned)(k & 0xFFFFFFFFull);
    }
  }
  __syncthreads();

  // decode boxes for top-100
  if (tid < KTOP) {
    unsigned idx = sid[tid];
    unsigned a = idx / 20u, lab = idx % 20u;
    float4 r  = ((const float4*)reg)[a];
    float4 an = ((const float4*)anch)[a];
    float cx = (sigm(r.x) + an.x) * STRIDEF;
    float cy = (sigm(r.y) + an.y) * STRIDEF;
    float w  = fexp(r.z) * an.z;
    float h  = fexp(r.w) * an.w;
    float x1 = cx - 0.5f * w, y1 = cy - 0.5f * h;
    float x2 = cx + 0.5f * w, y2 = cy + 0.5f * h;
    bx[tid][0] = x1; bx[tid][1] = y1; bx[tid][2] = x2; bx[tid][3] = y2;
    float off = (float)lab * COFF;
    float o0 = x1 + off, o1 = y1 + off, o2 = x2 + off, o3 = y2 + off;
    ob[tid][0] = o0; ob[tid][1] = o1; ob[tid][2] = o2; ob[tid][3] = o3;
    area[tid] = (o2 - o0) * (o3 - o1);
  }
  __syncthreads();

  // pairwise suppression mask (j > i only, per reference)
  for (int p = tid; p < KTOP * KTOP; p += 1024) {
    int i = p / KTOP, j = p % KTOP;
    if (j > i) {
      float xx1 = fmaxf(ob[i][0], ob[j][0]);
      float yy1 = fmaxf(ob[i][1], ob[j][1]);
      float xx2 = fminf(ob[i][2], ob[j][2]);
      float yy2 = fminf(ob[i][3], ob[j][3]);
      float w = fmaxf(1e-10f, xx2 - xx1);
      float h = fmaxf(1e-10f, yy2 - yy1);
      float inter = w * h;
      float iou = inter / (area[i] + area[j] - inter);
      if (iou > NMS_T) atomicOr(&sup[i][j >> 6], 1ull << (j & 63));
    }
  }
  __syncthreads();

  // serial greedy NMS over bitmasks (exactly the reference fori_loop)
  if (tid == 0) {
    unsigned long long k0 = 0ull, k1 = 0ull;
    for (int t = 0; t < 64; ++t)    if (sc[t] > CONF) k0 |= (1ull << t);
    for (int t = 64; t < KTOP; ++t) if (sc[t] > CONF) k1 |= (1ull << (t - 64));
    for (int i = 0; i < KTOP; ++i) {
      bool ki = (i < 64) ? ((k0 >> i) & 1ull) : ((k1 >> (i - 64)) & 1ull);
      if (ki) { k0 &= ~sup[i][0]; k1 &= ~sup[i][1]; }
    }
    keepm[0] = k0; keepm[1] = k1;
  }
  __syncthreads();

  if (tid < KTOP) {
    out[tid * 4 + 0] = bx[tid][0];
    out[tid * 4 + 1] = bx[tid][1];
    out[tid * 4 + 2] = bx[tid][2];
    out[tid * 4 + 3] = bx[tid][3];
    out[400 + tid] = sc[tid];
    out[500 + tid] = (float)(sid[tid] % 20u);
    bool kp = (tid < 64) ? ((keepm[0] >> tid) & 1ull)
                         : ((keepm[1] >> (tid - 64)) & 1ull);
    out[600 + tid] = kp ? 1.0f : 0.0f;
  }
}

extern "C" void kernel_launch(void* const* d_in, const int* in_sizes, int n_in,
                              void* d_out, int out_size, void* d_ws, size_t ws_size,
                              hipStream_t stream) {
  (void)in_sizes; (void)n_in; (void)out_size; (void)ws_size;
  const float* obj  = (const float*)d_in[0];
  const float* cls  = (const float*)d_in[1];
  const float* reg  = (const float*)d_in[2];
  const float* anch = (const float*)d_in[3];
  float* out = (float*)d_out;

  unsigned* meta   = (unsigned*)d_ws;
  unsigned* hist   = (unsigned*)((char*)d_ws + 64);
  float*    cscore = (float*)((char*)d_ws + 16448);
  unsigned* cidx   = (unsigned*)((char*)d_ws + 32832);

  hipMemsetAsync(meta, 0, 16, stream);
  hipLaunchKernelGGL(k_scan,     dim3(NQ / 256), dim3(256),  0, stream, obj, cls, meta, cscore, cidx);
  hipLaunchKernelGGL(k_check,    dim3(1),        dim3(256),  0, stream, meta, hist);
  hipLaunchKernelGGL(k_rhist,    dim3(256),      dim3(256),  0, stream, obj, cls, meta, hist);
  hipLaunchKernelGGL(k_rbstar,   dim3(1),        dim3(256),  0, stream, meta, hist);
  hipLaunchKernelGGL(k_rcollect, dim3(256),      dim3(256),  0, stream, obj, cls, meta, cscore, cidx);
  hipLaunchKernelGGL(k_final,    dim3(1),        dim3(1024), 0, stream, reg, anch, meta, cscore, cidx, out);
}